// Round 7
// baseline (339.439 us; speedup 1.0000x reference)
//
#include <hip/hip_runtime.h>
#include <stdint.h>

#define BB 512
#define TT 1024
#define KK 48
#define PF 4

// mask may arrive as 1-byte bools (raw numpy) or as 4-byte words.
// mask[0][0..3] are guaranteed true (len >= T/2), so the first 32-bit word is
// 0x01010101 iff byte storage.
__device__ __forceinline__ int mask_at(const void* m, int idx, bool bytes) {
    return bytes ? (int)(((const uint8_t*)m)[idx] != 0)
                 : (int)(((const int*)m)[idx] != 0);
}

// one-time wave broadcast (init only; not on the hot chain)
__device__ __forceinline__ float bcast(float v, int lane) {
    return __int_as_float(__builtin_amdgcn_readlane(__float_as_int(v), lane));
}

// ------------- forward algorithm + fused gold-path score -------------------
// One wave per batch row; lane j owns state j. Exp-domain recurrence
// p <- (E^T p) * exp(em_t), E = exp(trans) in 48 VGPRs.
//
// R2-R6 post-mortem: every readlane/SGPR-broadcast variant wrote ~44 MB of
// scratch to HBM per dispatch (semantic writes: 4 KB) and sat at ~510
// cyc/step regardless of launch_bounds / sched_barriers / RL grouping.
// R1's LDS version wrote 16 KB (no scratch). This version keeps the LDS
// broadcast but removes R1's two __syncthreads per step (single wave =>
// in-order per-wave LDS pipe; ds_write then ds_read_b128 observes the
// write, compiler orders via aliasing + sched_barrier) and removes the
// __shfl normalizer (r = s[0].x is lane-local: every lane loads all 48 p).
// Renorm every 4th step: growth/step <= 48*e^{0.1+5.5} ~= 2^14 — f32-safe.
__global__ __launch_bounds__(64, 1) void crf_fwd(
    const float* __restrict__ em, const int* __restrict__ tags,
    const void* __restrict__ mask, const float* __restrict__ trans,
    const float* __restrict__ start, const float* __restrict__ endt,
    float* __restrict__ ws)
{
    const int b = blockIdx.x;
    const int lane = threadIdx.x;
    const bool active = lane < KK;
    const int j = active ? lane : KK - 1;   // clamp for safe loads

    __shared__ __align__(16) float p_lds[64];

    const bool mb = (*(const int*)mask) == 0x01010101;

    // sequence length = popcount of prefix mask
    int cnt = 0;
    for (int t = lane; t < TT; t += 64) cnt += mask_at(mask, b * TT + t, mb);
    #pragma unroll
    for (int off = 32; off >= 1; off >>= 1) cnt += __shfl_xor(cnt, off);
    const int len = cnt;

    // E[i][j] = exp(trans[i][j]) for this lane's column j
    float etr[KK];
    #pragma unroll
    for (int i = 0; i < KK; ++i)
        etr[i] = active ? __expf(trans[i * KK + j]) : 0.0f;

    const float* emb = em + (size_t)b * TT * KK;

    // init: pcur = exp(S_0 - c), c = S_0[0]   (lanes >= KK carry pcur = 0)
    float s0i = start[j] + emb[j];
    float c = bcast(s0i, 0);
    float pcur = active ? __expf(s0i - c) : 0.0f;

    // emission prefetch pipeline keeps HBM/L2 latency off the serial chain
    float pipe[PF];
    #pragma unroll
    for (int d = 0; d < PF; ++d) pipe[d] = emb[(1 + d) * KK + j];

    const float4* __restrict__ p4 = (const float4*)p_lds;

    // one forward step: pcur <- (E^T pcur) * e [ * 1/p[0] if renorm ]
    auto step = [&](float e, bool renorm) {
        p_lds[lane] = pcur;                      // ds_write_b32
        __builtin_amdgcn_sched_barrier(0);       // write stays before reads
        float4 s[12];
        #pragma unroll
        for (int i = 0; i < 12; ++i) s[i] = p4[i];   // 12x ds_read_b128 (bcast)
        __builtin_amdgcn_sched_barrier(0);       // all reads issued up-front
        float scale = e;
        if (renorm) {
            scale *= __builtin_amdgcn_rcpf(s[0].x);  // r lane-local, no shfl
            c += __logf(s[0].x);                     // side chain
        }
        float q0 = s[0].x * etr[0];
        float q1 = s[0].y * etr[1];
        float q2 = s[0].z * etr[2];
        float q3 = s[0].w * etr[3];
        #pragma unroll
        for (int i = 1; i < 12; ++i) {
            q0 = fmaf(s[i].x, etr[4 * i],     q0);
            q1 = fmaf(s[i].y, etr[4 * i + 1], q1);
            q2 = fmaf(s[i].z, etr[4 * i + 2], q2);
            q3 = fmaf(s[i].w, etr[4 * i + 3], q3);
        }
        pcur = ((q0 + q1) + (q2 + q3)) * scale;
    };

    int t = 1;
    // ---- main loop: full PF-blocks, no per-substep guards ----
    while (t + PF <= len) {
        float eexp[PF];
        #pragma unroll
        for (int d = 0; d < PF; ++d) eexp[d] = __expf(pipe[d]);   // off-chain
        #pragma unroll
        for (int d = 0; d < PF; ++d) {
            int tt = t + PF + d; tt = tt < TT ? tt : TT - 1;
            pipe[d] = emb[tt * KK + j];
        }
        #pragma unroll
        for (int d = 0; d < PF; ++d) step(eexp[d], d == 0);
        t += PF;
    }
    // ---- tail: guarded, renorm every step (<= PF-1 steps) ----
    while (t < len) {
        float e = __expf(pipe[0]);
        #pragma unroll
        for (int d = 0; d < PF - 1; ++d) pipe[d] = pipe[d + 1];
        step(e, true);
        ++t;
    }

    // log_z = c + log(sum_j pcur_j * exp(end_j))   (inactive lanes: pcur = 0)
    float v = active ? pcur * __expf(endt[j]) : 0.0f;
    #pragma unroll
    for (int off = 32; off >= 1; off >>= 1) v += __shfl_xor(v, off);

    // ---- fused gold-path score (mask is prefix: m[t] == (t < len)) ----
    const int* tgb = tags + b * TT;
    float sq = 0.f;
    for (int tt2 = lane; tt2 < TT; tt2 += 64) {
        if (tt2 >= 1 && tt2 < len) {
            int tp = tgb[tt2 - 1], tc = tgb[tt2];
            sq += trans[tp * KK + tc] + emb[tt2 * KK + tc];
        }
    }
    #pragma unroll
    for (int off = 32; off >= 1; off >>= 1) sq += __shfl_xor(sq, off);

    if (lane == 0) {
        int t0 = tgb[0];
        ws[b]      = c + __logf(v);
        ws[BB + b] = sq + start[t0] + emb[t0] + endt[tgb[len - 1]];
    }
}

// ---------------- final mean reduction ----------------
__global__ __launch_bounds__(256) void crf_final(const float* __restrict__ ws,
                                                 float* __restrict__ out)
{
    __shared__ float red[256];
    float s = 0.f;
    for (int b = threadIdx.x; b < BB; b += 256) s += ws[b] - ws[BB + b];
    red[threadIdx.x] = s;
    __syncthreads();
    for (int off = 128; off > 0; off >>= 1) {
        if (threadIdx.x < off) red[threadIdx.x] += red[threadIdx.x + off];
        __syncthreads();
    }
    if (threadIdx.x == 0) out[0] = red[0] / (float)BB;
}

extern "C" void kernel_launch(void* const* d_in, const int* in_sizes, int n_in,
                              void* d_out, int out_size, void* d_ws, size_t ws_size,
                              hipStream_t stream) {
    const float* em    = (const float*)d_in[0];
    const int*   tags  = (const int*)d_in[1];
    const void*  mask  = d_in[2];
    const float* trans = (const float*)d_in[3];
    const float* start = (const float*)d_in[4];
    const float* endt  = (const float*)d_in[5];
    float* ws  = (float*)d_ws;
    float* out = (float*)d_out;

    crf_fwd  <<<BB, 64,  0, stream>>>(em, tags, mask, trans, start, endt, ws);
    crf_final<<<1,  256, 0, stream>>>(ws, out);
}

// Round 8
// 336.734 us; speedup vs baseline: 1.0080x; 1.0080x over previous
//
#include <hip/hip_runtime.h>
#include <stdint.h>

#define BB 512
#define TT 1024
#define KK 48
#define PF 4

// mask may arrive as 1-byte bools (raw numpy) or as 4-byte words.
// mask[0][0..3] are guaranteed true (len >= T/2), so the first 32-bit word is
// 0x01010101 iff byte storage.
__device__ __forceinline__ int mask_at(const void* m, int idx, bool bytes) {
    return bytes ? (int)(((const uint8_t*)m)[idx] != 0)
                 : (int)(((const int*)m)[idx] != 0);
}

// one-time wave broadcast (init only; not on the hot chain)
__device__ __forceinline__ float bcast(float v, int lane) {
    return __int_as_float(__builtin_amdgcn_readlane(__float_as_int(v), lane));
}

// ------------- forward algorithm + fused gold-path score -------------------
// One wave per batch row; lane j owns state j. Exp-domain recurrence
// p <- (E^T p) * exp(em_t), E = exp(trans) in 48 arch VGPRs.
//
// R7 post-mortem: WRITE_SIZE was KB all along (45 KB — no scratch ever).
// VGPR_Count stuck at 40-64 because the allocator budgets for 8 waves/EU
// (512/8=64) and parks etr[48] in AGPRs (unified file, invisible to
// VGPR_Count) — 48 v_accvgpr_read per step on the serial chain.
// amdgpu_waves_per_eu(1,1) clamps the occupancy target to 1 wave/EU
// (true anyway: 2 blocks/CU land on different SIMDs), giving the
// allocator ~512 VGPRs so etr stays arch-resident. No barrier after the
// LDS reads: compiler interleaves FMAs under progressive lgkmcnt.
// Renorm every 4th step: growth/step <= 48*e^{0.1+5.5} ~= 2^14 — f32-safe.
__global__ __launch_bounds__(64)
__attribute__((amdgpu_waves_per_eu(1, 1)))
void crf_fwd(
    const float* __restrict__ em, const int* __restrict__ tags,
    const void* __restrict__ mask, const float* __restrict__ trans,
    const float* __restrict__ start, const float* __restrict__ endt,
    float* __restrict__ ws)
{
    const int b = blockIdx.x;
    const int lane = threadIdx.x;
    const bool active = lane < KK;
    const int j = active ? lane : KK - 1;   // clamp for safe loads

    __shared__ __align__(16) float p_lds[64];

    const bool mb = (*(const int*)mask) == 0x01010101;

    // sequence length = popcount of prefix mask
    int cnt = 0;
    for (int t = lane; t < TT; t += 64) cnt += mask_at(mask, b * TT + t, mb);
    #pragma unroll
    for (int off = 32; off >= 1; off >>= 1) cnt += __shfl_xor(cnt, off);
    const int len = cnt;

    // E[i][j] = exp(trans[i][j]) for this lane's column j — arch VGPRs
    float etr[KK];
    #pragma unroll
    for (int i = 0; i < KK; ++i)
        etr[i] = active ? __expf(trans[i * KK + j]) : 0.0f;

    const float* emb = em + (size_t)b * TT * KK;

    // init: pcur = exp(S_0 - c), c = S_0[0]   (lanes >= KK carry pcur = 0)
    float s0i = start[j] + emb[j];
    float c = bcast(s0i, 0);
    float pcur = active ? __expf(s0i - c) : 0.0f;

    const float4* __restrict__ p4 = (const float4*)p_lds;

    // prefetch pointer: advances by PF rows; loads use immediate offsets
    const float* pf = emb + KK + j;          // row t=1, this lane's state
    float pipe[PF];
    #pragma unroll
    for (int d = 0; d < PF; ++d) pipe[d] = pf[d * KK];
    pf += PF * KK;

    // one forward step: pcur <- (E^T pcur) * e [ * 1/p[0] if renorm ]
    auto step = [&](float e, bool renorm) {
        p_lds[lane] = pcur;                      // ds_write_b32
        __builtin_amdgcn_sched_barrier(0);       // write stays before reads
        float4 s[12];
        #pragma unroll
        for (int i = 0; i < 12; ++i) s[i] = p4[i];   // 12x ds_read_b128
        // no barrier: FMAs interleave with reads under progressive lgkmcnt
        float scale = e;
        if (renorm) {
            scale *= __builtin_amdgcn_rcpf(s[0].x);  // lane-local, no shfl
            c += __logf(s[0].x);                     // side chain
        }
        float q0 = s[0].x * etr[0];
        float q1 = s[0].y * etr[1];
        float q2 = s[0].z * etr[2];
        float q3 = s[0].w * etr[3];
        #pragma unroll
        for (int i = 1; i < 12; ++i) {
            q0 = fmaf(s[i].x, etr[4 * i],     q0);
            q1 = fmaf(s[i].y, etr[4 * i + 1], q1);
            q2 = fmaf(s[i].z, etr[4 * i + 2], q2);
            q3 = fmaf(s[i].w, etr[4 * i + 3], q3);
        }
        pcur = ((q0 + q1) + (q2 + q3)) * scale;
    };

    int t = 1;
    // ---- main loop: prefetch always in-bounds (t+PF+d <= len-1) ----
    while (t + 2 * PF <= len) {
        float eexp[PF];
        #pragma unroll
        for (int d = 0; d < PF; ++d) eexp[d] = __expf(pipe[d]);   // off-chain
        #pragma unroll
        for (int d = 0; d < PF; ++d) pipe[d] = pf[d * KK];
        pf += PF * KK;
        #pragma unroll
        for (int d = 0; d < PF; ++d) step(eexp[d], d == 0);
        t += PF;
    }
    // ---- drain the pipe (holds emissions for t..t+PF-1) ----
    #pragma unroll
    for (int pi = 0; pi < PF; ++pi) {
        if (t < len) { step(__expf(pipe[pi]), true); ++t; }
    }
    // ---- direct-load tail (<= PF-1 steps) ----
    while (t < len) {
        step(__expf(emb[t * KK + j]), true);
        ++t;
    }

    // log_z = c + log(sum_j pcur_j * exp(end_j))   (inactive lanes: pcur = 0)
    float v = active ? pcur * __expf(endt[j]) : 0.0f;
    #pragma unroll
    for (int off = 32; off >= 1; off >>= 1) v += __shfl_xor(v, off);

    // ---- fused gold-path score (mask is prefix: m[t] == (t < len)) ----
    const int* tgb = tags + b * TT;
    float sq = 0.f;
    for (int tt2 = lane; tt2 < TT; tt2 += 64) {
        if (tt2 >= 1 && tt2 < len) {
            int tp = tgb[tt2 - 1], tc = tgb[tt2];
            sq += trans[tp * KK + tc] + emb[tt2 * KK + tc];
        }
    }
    #pragma unroll
    for (int off = 32; off >= 1; off >>= 1) sq += __shfl_xor(sq, off);

    if (lane == 0) {
        int t0 = tgb[0];
        ws[b]      = c + __logf(v);
        ws[BB + b] = sq + start[t0] + emb[t0] + endt[tgb[len - 1]];
    }
}

// ---------------- final mean reduction ----------------
__global__ __launch_bounds__(256) void crf_final(const float* __restrict__ ws,
                                                 float* __restrict__ out)
{
    __shared__ float red[256];
    float s = 0.f;
    for (int b = threadIdx.x; b < BB; b += 256) s += ws[b] - ws[BB + b];
    red[threadIdx.x] = s;
    __syncthreads();
    for (int off = 128; off > 0; off >>= 1) {
        if (threadIdx.x < off) red[threadIdx.x] += red[threadIdx.x + off];
        __syncthreads();
    }
    if (threadIdx.x == 0) out[0] = red[0] / (float)BB;
}

extern "C" void kernel_launch(void* const* d_in, const int* in_sizes, int n_in,
                              void* d_out, int out_size, void* d_ws, size_t ws_size,
                              hipStream_t stream) {
    const float* em    = (const float*)d_in[0];
    const int*   tags  = (const int*)d_in[1];
    const void*  mask  = d_in[2];
    const float* trans = (const float*)d_in[3];
    const float* start = (const float*)d_in[4];
    const float* endt  = (const float*)d_in[5];
    float* ws  = (float*)d_ws;
    float* out = (float*)d_out;

    crf_fwd  <<<BB, 64,  0, stream>>>(em, tags, mask, trans, start, endt, ws);
    crf_final<<<1,  256, 0, stream>>>(ws, out);
}